// Round 2
// baseline (2426.078 us; speedup 1.0000x reference)
//
#include <hip/hip_runtime.h>
#include <cstdint>

typedef __attribute__((ext_vector_type(8))) short bf16x8;
typedef __attribute__((ext_vector_type(4))) float f32x4;
typedef unsigned short u16;
typedef unsigned int u32;
typedef unsigned long long u64;

#define T_STEPS 256
#define BATCH 64
#define HID 256
#define VOCAB 5000
#define KC 768            // 3*HID (ker/rker/bias row stride)
#define NWG 16

// ---------- helpers ----------
__device__ __forceinline__ u16 f2bf(float x) {
  union { float f; u32 u; } v; v.f = x;
  u32 r = v.u + 0x7fffu + ((v.u >> 16) & 1u);
  return (u16)(r >> 16);
}
__device__ __forceinline__ float bf2f(u16 b) {
  union { float f; u32 u; } v; v.u = ((u32)b) << 16;
  return v.f;
}
__device__ __forceinline__ u32 packhl(float x) {
  u16 hi = f2bf(x);
  u16 lo = f2bf(x - bf2f(hi));
  return (u32)hi | ((u32)lo << 16);
}
__device__ __forceinline__ void load_lds16(const void* g, void* l) {
  __builtin_amdgcn_global_load_lds(
      (const __attribute__((address_space(1))) void*)g,
      (__attribute__((address_space(3))) void*)l, 16, 0, 0);
}
__device__ __forceinline__ u64 ald64(const u32* p) {
  return __hip_atomic_load((const u64*)p, __ATOMIC_RELAXED, __HIP_MEMORY_SCOPE_AGENT);
}
__device__ __forceinline__ float sigm(float x) { return 1.f / (1.f + __expf(-x)); }
__device__ __forceinline__ float tanh_f(float x) {
  return 2.f / (1.f + __expf(-2.f * x)) - 1.f;
}

// ---------- prep: BT[n][512] u16 = [Whi(256) | Wlo(256)], seg-swizzled ----------
// u16 seg (8 u16 = 16B) s within each 4-seg (64B) block stored at s ^ ((n>>1)&3)
__global__ __launch_bounds__(256) void prep_b(const float* __restrict__ Wd,
                                              u16* __restrict__ BT) {
  int gid = blockIdx.x * 256 + threadIdx.x;   // 64 segs * 5120 n
  int segp = gid / 5120;                      // physical seg 0..63
  int n = gid % 5120;
  int blk = segp >> 2, sp = segp & 3;
  int sl = sp ^ ((n >> 1) & 3);               // logical seg within block
  int cl = (blk * 4 + sl) * 8;                // logical u16 col base
  union { uint4 q; u16 s[8]; } o;
#pragma unroll
  for (int i = 0; i < 8; ++i) {
    int c = cl + i;
    int k = c & 255;
    float x = (n < VOCAB) ? Wd[k * VOCAB + n] : 0.f;
    u16 hi = f2bf(x);
    o.s[i] = (c < 256) ? hi : f2bf(x - bf2f(hi));
  }
  *(uint4*)(BT + (size_t)n * 512 + segp * 8) = o.q;
}

// ---------- prep: H0S[b][256] packed u32, seg-swizzled like AbufP ----------
__global__ __launch_bounds__(256) void prep_h0(const float* __restrict__ h0,
                                               u32* __restrict__ H0S) {
  int i = blockIdx.x * 256 + threadIdx.x;  // 16384
  int b = i >> 8, j = i & 255;
  u32 val = packhl(h0[i]);
  int segG = j >> 2;
  int segS = (segG & ~7) | ((segG & 7) ^ (b & 7));
  H0S[(size_t)b * 256 + segS * 4 + (j & 3)] = val;
}

// ---------- recurrence: 16 WGs hidden-split, all-atomic h exchange ----------
__global__ __launch_bounds__(256, 1) void gru_rec(
    const int* __restrict__ tokens, const float* __restrict__ h0,
    const float* __restrict__ ker, const float* __restrict__ rker,
    const float* __restrict__ bias,
    u32* __restrict__ AbufP, const u32* __restrict__ H0S,
    float* __restrict__ hlast, u32* __restrict__ flags) {
  const int g = blockIdx.x;
  const int tid = threadIdx.x;
  const int w = tid >> 6;
  const int l = tid & 63;
  const int lm = l & 15;
  const int lq = l >> 4;
  const int r7 = lm & 7;

  int cmap[3]; float brec[3], bin[3];
#pragma unroll
  for (int nt = 0; nt < 3; ++nt) {
    cmap[nt] = nt * 256 + g * 16 + lm;
    bin[nt]  = bias[cmap[nt]];
    brec[nt] = bias[KC + cmap[nt]];
  }

  // Step-invariant B-fragments (rkernel hi/lo), B[k][n]: n=lane&15, k=quad*8+j
  bf16x8 Bhi[3][8], Blo[3][8];
#pragma unroll
  for (int nt = 0; nt < 3; ++nt)
#pragma unroll
    for (int kb = 0; kb < 8; ++kb) {
      union { bf16x8 v; u16 s[8]; } uh, ul;
#pragma unroll
      for (int jj = 0; jj < 8; ++jj) {
        int k = kb * 32 + lq * 8 + jj;
        float x = rker[k * KC + cmap[nt]];
        u16 hi = f2bf(x);
        uh.s[jj] = hi;
        ul.s[jj] = f2bf(x - bf2f(hi));
      }
      Bhi[nt][kb] = uh.v; Blo[nt][kb] = ul.v;
    }

  float hown[4];
#pragma unroll
  for (int r = 0; r < 4; ++r)
    hown[r] = h0[(16 * w + lq * 4 + r) * HID + g * 16 + lm];

  // first embedding gather (t=0)
  float mx[3][4];
#pragma unroll
  for (int r = 0; r < 4; ++r) {
    int b = 16 * w + lq * 4 + r;
    int tok = tokens[b * T_STEPS + 0];
#pragma unroll
    for (int nt = 0; nt < 3; ++nt)
      mx[nt][r] = ker[(size_t)tok * KC + cmap[nt]] + bin[nt];
  }

  for (int t = 0; t < T_STEPS; ++t) {
    if (t > 0) {
      const u32 tt = (u32)t;
      int guard = 0;
      for (;;) {
        u32 v = tt;
        if (l < 16)
          v = __hip_atomic_load(&flags[l * 32], __ATOMIC_RELAXED,
                                __HIP_MEMORY_SCOPE_AGENT);
        if (__all((int)(v >= tt))) break;
        if (++guard > (1 << 24)) break;   // safety valve
        __builtin_amdgcn_s_sleep(1);
      }
    }

    // issue all 32 coherent loads of previous h (packed, swizzled)
    const u32* src = ((t == 0) ? H0S : (AbufP + (size_t)(t - 1) * BATCH * 256))
                     + (size_t)(16 * w + lm) * 256;
    u64 raw[32];
#pragma unroll
    for (int kb = 0; kb < 8; ++kb) {
      int s0 = kb * 8 + ((lq * 2) ^ r7);
      int s1 = kb * 8 + (((lq * 2) | 1) ^ r7);
      raw[kb * 4 + 0] = ald64(src + s0 * 4);
      raw[kb * 4 + 1] = ald64(src + s0 * 4 + 2);
      raw[kb * 4 + 2] = ald64(src + s1 * 4);
      raw[kb * 4 + 3] = ald64(src + s1 * 4 + 2);
    }

    f32x4 acc[3];
#pragma unroll
    for (int nt = 0; nt < 3; ++nt)
      acc[nt] = (f32x4){brec[nt], brec[nt], brec[nt], brec[nt]};

#pragma unroll
    for (int kb = 0; kb < 8; ++kb) {
      u32 p[8];
      p[0] = (u32)raw[kb * 4 + 0]; p[1] = (u32)(raw[kb * 4 + 0] >> 32);
      p[2] = (u32)raw[kb * 4 + 1]; p[3] = (u32)(raw[kb * 4 + 1] >> 32);
      p[4] = (u32)raw[kb * 4 + 2]; p[5] = (u32)(raw[kb * 4 + 2] >> 32);
      p[6] = (u32)raw[kb * 4 + 3]; p[7] = (u32)(raw[kb * 4 + 3] >> 32);
      union { u32 u[4]; bf16x8 v; } hi, lo;
#pragma unroll
      for (int i = 0; i < 4; ++i) {
        hi.u[i] = (p[2 * i] & 0xffffu) | (p[2 * i + 1] << 16);
        lo.u[i] = (p[2 * i] >> 16) | (p[2 * i + 1] & 0xffff0000u);
      }
#pragma unroll
      for (int nt = 0; nt < 3; ++nt) {
        acc[nt] = __builtin_amdgcn_mfma_f32_16x16x32_bf16(hi.v, Bhi[nt][kb], acc[nt], 0, 0, 0);
        acc[nt] = __builtin_amdgcn_mfma_f32_16x16x32_bf16(lo.v, Bhi[nt][kb], acc[nt], 0, 0, 0);
        acc[nt] = __builtin_amdgcn_mfma_f32_16x16x32_bf16(hi.v, Blo[nt][kb], acc[nt], 0, 0, 0);
      }
    }

#pragma unroll
    for (int r = 0; r < 4; ++r) {
      float z  = sigm(acc[0][r] + mx[0][r]);
      float rg = sigm(acc[1][r] + mx[1][r]);
      float cd = tanh_f(mx[2][r] + rg * acc[2][r]);
      float hn = z * hown[r] + (1.f - z) * cd;
      hown[r] = hn;
      int b = 16 * w + lq * 4 + r;
      int segG = g * 4 + (lm >> 2);
      int segS = (segG & ~7) | ((segG & 7) ^ (b & 7));
      __hip_atomic_store(AbufP + (size_t)(t * BATCH + b) * 256 + segS * 4 + (lm & 3),
                         packhl(hn), __ATOMIC_RELAXED, __HIP_MEMORY_SCOPE_AGENT);
    }

    __syncthreads();   // drains each wave's vmcnt before barrier
    if (tid == 0)
      __hip_atomic_store(&flags[g * 32], (u32)(t + 1), __ATOMIC_RELEASE,
                         __HIP_MEMORY_SCOPE_AGENT);

    // prefetch next step's embedding gather (hidden behind next spin)
    if (t + 1 < T_STEPS) {
#pragma unroll
      for (int r = 0; r < 4; ++r) {
        int b = 16 * w + lq * 4 + r;
        int tok = tokens[b * T_STEPS + t + 1];
#pragma unroll
        for (int nt = 0; nt < 3; ++nt)
          mx[nt][r] = ker[(size_t)tok * KC + cmap[nt]] + bin[nt];
      }
    }
  }

#pragma unroll
  for (int r = 0; r < 4; ++r) {
    int b = 16 * w + lq * 4 + r;
    hlast[b * HID + g * 16 + lm] = hown[r];
  }
}

// ---------- final GEMM: out[16384,5000] = unpack(A)[.,256] @ B + bd, 3 products ----------
__global__ __launch_bounds__(256, 2) void gemm_out(
    const u32* __restrict__ A, const u16* __restrict__ BT,
    const float* __restrict__ bd, float* __restrict__ out) {
  __shared__ u32 Ap[128 * 32];   // 16 KB, swizzled 128-B rows
  __shared__ u16 Bh[128 * 32];   // 8 KB
  __shared__ u16 Bl[128 * 32];   // 8 KB
  const int tid = threadIdx.x;
  const int w = tid >> 6, l = tid & 63;
  const int lm = l & 15, lq = l >> 4;
  const int wm = w & 1, wn = w >> 1;
  const int m0 = blockIdx.y * 128;
  const int n0 = blockIdx.x * 128;
  const int r7 = lm & 7;
  const int b3 = (lm >> 1) & 3;

  f32x4 acc[4][4] = {};

  for (int kb = 0; kb < 8; ++kb) {
    if (kb) __syncthreads();
#pragma unroll
    for (int p = 0; p < 4; ++p) {
      int c = p * 256 + tid;
      int row = c >> 3, seg = c & 7;
      load_lds16(A + (size_t)(m0 + row) * 256 + kb * 32 + seg * 4, Ap + c * 4);
    }
#pragma unroll
    for (int p = 0; p < 2; ++p) {
      int c = p * 256 + tid;
      int row = c >> 2, sg = c & 3;
      const u16* bsrc = BT + (size_t)(n0 + row) * 512 + kb * 32 + sg * 8;
      load_lds16(bsrc, Bh + c * 8);
      load_lds16(bsrc + 256, Bl + c * 8);
    }
    __syncthreads();

    bf16x8 ah[4], al[4], bh[4], bl[4];
#pragma unroll
    for (int mi = 0; mi < 4; ++mi) {
      int row = wm * 64 + mi * 16 + lm;
      int ls0 = (lq * 2) ^ r7;
      int ls1 = ls0 ^ 1;
      uint4 q0 = *(const uint4*)(Ap + row * 32 + ls0 * 4);
      uint4 q1 = *(const uint4*)(Ap + row * 32 + ls1 * 4);
      u32 p[8] = {q0.x, q0.y, q0.z, q0.w, q1.x, q1.y, q1.z, q1.w};
      union { u32 u[4]; bf16x8 v; } hi, lo;
#pragma unroll
      for (int i = 0; i < 4; ++i) {
        hi.u[i] = (p[2 * i] & 0xffffu) | (p[2 * i + 1] << 16);
        lo.u[i] = (p[2 * i] >> 16) | (p[2 * i + 1] & 0xffff0000u);
      }
      ah[mi] = hi.v; al[mi] = lo.v;
    }
#pragma unroll
    for (int ni = 0; ni < 4; ++ni) {
      int row = wn * 64 + ni * 16 + lm;
      int ls = lq ^ b3;
      bh[ni] = *(const bf16x8*)(Bh + row * 32 + ls * 8);
      bl[ni] = *(const bf16x8*)(Bl + row * 32 + ls * 8);
    }
#pragma unroll
    for (int mi = 0; mi < 4; ++mi)
#pragma unroll
      for (int ni = 0; ni < 4; ++ni) {
        acc[mi][ni] = __builtin_amdgcn_mfma_f32_16x16x32_bf16(ah[mi], bh[ni], acc[mi][ni], 0, 0, 0);
        acc[mi][ni] = __builtin_amdgcn_mfma_f32_16x16x32_bf16(al[mi], bh[ni], acc[mi][ni], 0, 0, 0);
        acc[mi][ni] = __builtin_amdgcn_mfma_f32_16x16x32_bf16(ah[mi], bl[ni], acc[mi][ni], 0, 0, 0);
      }
  }

#pragma unroll
  for (int ni = 0; ni < 4; ++ni) {
    int n = n0 + wn * 64 + ni * 16 + lm;
    float bdv = (n < VOCAB) ? bd[n] : 0.f;
#pragma unroll
    for (int mi = 0; mi < 4; ++mi) {
#pragma unroll
      for (int r = 0; r < 4; ++r) {
        int m = m0 + wm * 64 + mi * 16 + lq * 4 + r;
        if (n < VOCAB) out[(size_t)m * VOCAB + n] = acc[mi][ni][r] + bdv;
      }
    }
  }
}

// ---------- launch ----------
extern "C" void kernel_launch(void* const* d_in, const int* in_sizes, int n_in,
                              void* d_out, int out_size, void* d_ws, size_t ws_size,
                              hipStream_t stream) {
  const int*   tokens = (const int*)d_in[0];
  const float* h0     = (const float*)d_in[1];
  const float* ker    = (const float*)d_in[2];
  const float* rker   = (const float*)d_in[3];
  const float* bias   = (const float*)d_in[4];
  const float* Wd     = (const float*)d_in[5];
  const float* bd     = (const float*)d_in[6];
  float* out = (float*)d_out;
  char* ws = (char*)d_ws;

  // workspace layout (bytes)
  u32* AbufP = (u32*)(ws);               // 16384*256*4 = 16,777,216
  u16* BT    = (u16*)(ws + 16777216);    //  5120*512*2 =  5,242,880
  u32* H0S   = (u32*)(ws + 22020096);    //    64*256*4 =     65,536
  u32* flags = (u32*)(ws + 22085632);    //                   2,048

  hipMemsetAsync(flags, 0, 2048, stream);
  prep_b<<<1280, 256, 0, stream>>>(Wd, BT);
  prep_h0<<<64, 256, 0, stream>>>(h0, H0S);
  gru_rec<<<NWG, 256, 0, stream>>>(tokens, h0, ker, rker, bias, AbufP, H0S,
                                   out + (size_t)16384 * VOCAB, flags);
  gemm_out<<<dim3(40, 128), 256, 0, stream>>>(AbufP, BT, bd, out);
}